// Round 15
// baseline (1497.744 us; speedup 1.0000x reference)
//
#include <hip/hip_runtime.h>
#include <cstdint>
#include <cstddef>

typedef __bf16 bf16x8 __attribute__((ext_vector_type(8)));
typedef float f32x4 __attribute__((ext_vector_type(4)));
typedef unsigned short u16x8 __attribute__((ext_vector_type(8)));
typedef unsigned short u16x4 __attribute__((ext_vector_type(4)));
typedef unsigned int u32x4 __attribute__((ext_vector_type(4)));

#define BSTRIDE 52 // bias/mask row stride (elements)
#define BSZ 2548   // 49*52 per head / per window

__device__ __forceinline__ unsigned short f2bf(float f) {
  unsigned int u = __builtin_bit_cast(unsigned int, f);
  u += 0x7FFFu + ((u >> 16) & 1u);   // RNE
  return (unsigned short)(u >> 16);
}
__device__ __forceinline__ float bf2f(unsigned short h) {
  unsigned int u = (unsigned int)h << 16;
  return __builtin_bit_cast(float, u);
}
__device__ __forceinline__ unsigned pkbf(float a, float b) {
  return (unsigned)f2bf(a) | ((unsigned)f2bf(b) << 16);
}

// REGROUP: from two GEMM D-tiles (m-dim runs 4g+r per 16-block) to an MFMA
// operand fragment (k-dim runs 8g..8g+7 over the 32-m pair).
// In:  d0[r] = X[mbase +      4g + r][q],  d1[r] = X[mbase + 16 + 4g + r][q]
// Out: lane(q,g) holds bf16 X[mbase + 8g + j][q], j = 0..7.
// Derivation: m = 8g+j -> tile t = g>>1, src g' = (2g + (j>>2)) & 3, r = j&3.
__device__ __forceinline__ bf16x8 regroup(f32x4 d0, f32x4 d1, int q, int g) {
  unsigned u00 = pkbf(d0[0], d0[1]), u01 = pkbf(d0[2], d0[3]);
  unsigned u10 = pkbf(d1[0], d1[1]), u11 = pkbf(d1[2], d1[3]);
  int sA = q + (((2 * g) & 3) << 4);
  int sB = q + (((2 * g + 1) & 3) << 4);
  unsigned a00 = (unsigned)__shfl((int)u00, sA, 64);
  unsigned a01 = (unsigned)__shfl((int)u01, sA, 64);
  unsigned a10 = (unsigned)__shfl((int)u10, sA, 64);
  unsigned a11 = (unsigned)__shfl((int)u11, sA, 64);
  unsigned b00 = (unsigned)__shfl((int)u00, sB, 64);
  unsigned b01 = (unsigned)__shfl((int)u01, sB, 64);
  unsigned b10 = (unsigned)__shfl((int)u10, sB, 64);
  unsigned b11 = (unsigned)__shfl((int)u11, sB, 64);
  bool hi = g >= 2;
  u32x4 o;
  o[0] = hi ? a10 : a00;
  o[1] = hi ? a11 : a01;
  o[2] = hi ? b10 : b00;
  o[3] = hi ? b11 : b01;
  return __builtin_bit_cast(bf16x8, o);
}

// ---------------- kernel 0: generic fp32 -> bf16 (vec8, grid-stride) ----------------
__global__ void conv_f2b_k(const float* __restrict__ src, unsigned short* __restrict__ dst, long n8) {
  long i = (long)blockIdx.x * blockDim.x + threadIdx.x;
  long stride = (long)gridDim.x * blockDim.x;
  for (; i < n8; i += stride) {
    float4 a = *(const float4*)(src + i * 8);
    float4 b = *(const float4*)(src + i * 8 + 4);
    u16x8 p;
    p[0]=f2bf(a.x); p[1]=f2bf(a.y); p[2]=f2bf(a.z); p[3]=f2bf(a.w);
    p[4]=f2bf(b.x); p[5]=f2bf(b.y); p[6]=f2bf(b.z); p[7]=f2bf(b.w);
    *(u16x8*)(dst + i * 8) = p;
  }
}

// ---------------- kernel 0b: bias table bf16 [16][49][52] (pad cols 49..51 = 0) ----------------
__global__ void build_bias_k(const float* __restrict__ rpb, unsigned short* __restrict__ biasT) {
  int idx = blockIdx.x * 256 + threadIdx.x;
  if (idx >= 16 * BSZ) return;
  int h = idx / BSZ;
  int rem = idx - h * BSZ;
  int i = rem / BSTRIDE, j = rem - (rem / BSTRIDE) * BSTRIDE;
  unsigned short v = 0;
  if (j < 49) {
    int r1 = i / 7, c1 = i - r1 * 7;
    int r2 = j / 7, c2 = j - r2 * 7;
    int ri = (r1 - r2 + 6) * 13 + (c1 - c2 + 6);
    v = f2bf(rpb[ri * 16 + h]);
  }
  biasT[idx] = v;
}

// ---------------- kernel 0c: padded fp32 mask [64][49][52] (16B-aligned rows) ----------------
__global__ void build_maskp_k(const float* __restrict__ mask, float* __restrict__ maskp) {
  int idx = blockIdx.x * 256 + threadIdx.x;   // grid exact: 64*2548 = 637*256
  int w = idx / BSZ;
  int rem = idx - w * BSZ;
  int i = rem / BSTRIDE, j = rem - (rem / BSTRIDE) * BSTRIDE;
  maskp[idx] = (j < 49) ? mask[w * 2401 + i * 49 + j] : 0.0f;
}

// ---------------- fused kernel: per-window QKV projection + attention ----------------
// One block per window (512 thr, 8 waves). Wave wv owns heads {2wv, 2wv+1}.
// No LDS, no barriers: Q/K/V live entirely in registers via regroup().
__global__ __launch_bounds__(512, 2) void fused_qkv_attn_k(
    const float* __restrict__ x, const float* __restrict__ qkv_b,
    const unsigned short* __restrict__ wb, const unsigned short* __restrict__ biasT,
    const float* __restrict__ maskp, float* __restrict__ out)
{
  int b = blockIdx.x;
  int t = threadIdx.x;
  int lane = t & 63, wv = t >> 6;   // wv 0..7
  int g = lane >> 4, q = lane & 15;
  const float NINF = -__builtin_inff();
  f32x4 zero = {0.f, 0.f, 0.f, 0.f};

  // clamped rows (M=64 padded, rows 49..63 duplicate row 48; outputs masked/skipped)
  int rc[4];
  rc[0] = q; rc[1] = 16 + q; rc[2] = 32 + q; rc[3] = 48;
  const float* xr[4];
  #pragma unroll
  for (int it = 0; it < 4; ++it) xr[it] = x + ((size_t)b * 49 + rc[it]) * 512;
  const float* wm = maskp + (size_t)(b & 63) * BSZ;

  #pragma unroll
  for (int hh = 0; hh < 2; ++hh) {
    int h = wv * 2 + hh;
    bf16x8 bq[4], ak[4], bv[2][2];

    // ---------- pass Q (acc D: m=d from A=wf, n=i from B=xf) ----------
    {
      f32x4 acc[4][2] = {};
      const unsigned short* wq = wb + (size_t)(h * 32 + q) * 512;
      #pragma unroll
      for (int kt = 0; kt < 16; ++kt) {
        int ko = kt * 32 + 8 * g;
        bf16x8 xf[4], wf[2];
        #pragma unroll
        for (int it = 0; it < 4; ++it) {
          float4 A = *(const float4*)(xr[it] + ko);
          float4 B = *(const float4*)(xr[it] + ko + 4);
          u32x4 xo;
          xo[0] = pkbf(A.x, A.y); xo[1] = pkbf(A.z, A.w);
          xo[2] = pkbf(B.x, B.y); xo[3] = pkbf(B.z, B.w);
          xf[it] = __builtin_bit_cast(bf16x8, xo);
        }
        #pragma unroll
        for (int dt = 0; dt < 2; ++dt) wf[dt] = *(const bf16x8*)(wq + dt * 8192 + ko);
        __builtin_amdgcn_s_setprio(1);
        #pragma unroll
        for (int it = 0; it < 4; ++it)
          #pragma unroll
          for (int dt = 0; dt < 2; ++dt)
            acc[it][dt] = __builtin_amdgcn_mfma_f32_16x16x32_bf16(wf[dt], xf[it], acc[it][dt], 0, 0, 0);
        __builtin_amdgcn_s_setprio(0);
      }
      float4 bi0 = *(const float4*)(qkv_b + h * 32 + 4 * g);
      float4 bi1 = *(const float4*)(qkv_b + h * 32 + 16 + 4 * g);
      const float sc = 0.17677669529663687f;
      #pragma unroll
      for (int it = 0; it < 4; ++it) {
        f32x4 d0, d1;
        d0[0] = (acc[it][0][0] + bi0.x) * sc; d0[1] = (acc[it][0][1] + bi0.y) * sc;
        d0[2] = (acc[it][0][2] + bi0.z) * sc; d0[3] = (acc[it][0][3] + bi0.w) * sc;
        d1[0] = (acc[it][1][0] + bi1.x) * sc; d1[1] = (acc[it][1][1] + bi1.y) * sc;
        d1[2] = (acc[it][1][2] + bi1.z) * sc; d1[3] = (acc[it][1][3] + bi1.w) * sc;
        bq[it] = regroup(d0, d1, q, g);
      }
    }

    // ---------- pass K (same orientation, col base 512) ----------
    {
      f32x4 acc[4][2] = {};
      const unsigned short* wq = wb + (size_t)(512 + h * 32 + q) * 512;
      #pragma unroll
      for (int kt = 0; kt < 16; ++kt) {
        int ko = kt * 32 + 8 * g;
        bf16x8 xf[4], wf[2];
        #pragma unroll
        for (int it = 0; it < 4; ++it) {
          float4 A = *(const float4*)(xr[it] + ko);
          float4 B = *(const float4*)(xr[it] + ko + 4);
          u32x4 xo;
          xo[0] = pkbf(A.x, A.y); xo[1] = pkbf(A.z, A.w);
          xo[2] = pkbf(B.x, B.y); xo[3] = pkbf(B.z, B.w);
          xf[it] = __builtin_bit_cast(bf16x8, xo);
        }
        #pragma unroll
        for (int dt = 0; dt < 2; ++dt) wf[dt] = *(const bf16x8*)(wq + dt * 8192 + ko);
        __builtin_amdgcn_s_setprio(1);
        #pragma unroll
        for (int jt = 0; jt < 4; ++jt)
          #pragma unroll
          for (int dt = 0; dt < 2; ++dt)
            acc[jt][dt] = __builtin_amdgcn_mfma_f32_16x16x32_bf16(wf[dt], xf[jt], acc[jt][dt], 0, 0, 0);
        __builtin_amdgcn_s_setprio(0);
      }
      float4 bi0 = *(const float4*)(qkv_b + 512 + h * 32 + 4 * g);
      float4 bi1 = *(const float4*)(qkv_b + 512 + h * 32 + 16 + 4 * g);
      #pragma unroll
      for (int jt = 0; jt < 4; ++jt) {
        f32x4 d0, d1;
        d0[0] = acc[jt][0][0] + bi0.x; d0[1] = acc[jt][0][1] + bi0.y;
        d0[2] = acc[jt][0][2] + bi0.z; d0[3] = acc[jt][0][3] + bi0.w;
        d1[0] = acc[jt][1][0] + bi1.x; d1[1] = acc[jt][1][1] + bi1.y;
        d1[2] = acc[jt][1][2] + bi1.z; d1[3] = acc[jt][1][3] + bi1.w;
        ak[jt] = regroup(d0, d1, q, g);
      }
    }

    // ---------- pass V (acc D: m=j from A=xf, n=d from B=wf) ----------
    {
      f32x4 acc[4][2] = {};
      const unsigned short* wq = wb + (size_t)(1024 + h * 32 + q) * 512;
      #pragma unroll
      for (int kt = 0; kt < 16; ++kt) {
        int ko = kt * 32 + 8 * g;
        bf16x8 xf[4], wf[2];
        #pragma unroll
        for (int jt = 0; jt < 4; ++jt) {
          float4 A = *(const float4*)(xr[jt] + ko);
          float4 B = *(const float4*)(xr[jt] + ko + 4);
          u32x4 xo;
          xo[0] = pkbf(A.x, A.y); xo[1] = pkbf(A.z, A.w);
          xo[2] = pkbf(B.x, B.y); xo[3] = pkbf(B.z, B.w);
          xf[jt] = __builtin_bit_cast(bf16x8, xo);
        }
        #pragma unroll
        for (int dt = 0; dt < 2; ++dt) wf[dt] = *(const bf16x8*)(wq + dt * 8192 + ko);
        __builtin_amdgcn_s_setprio(1);
        #pragma unroll
        for (int jt = 0; jt < 4; ++jt)
          #pragma unroll
          for (int dt = 0; dt < 2; ++dt)
            acc[jt][dt] = __builtin_amdgcn_mfma_f32_16x16x32_bf16(xf[jt], wf[dt], acc[jt][dt], 0, 0, 0);
        __builtin_amdgcn_s_setprio(0);
      }
      float vb0 = qkv_b[1024 + h * 32 + q];
      float vb1 = qkv_b[1024 + h * 32 + 16 + q];
      #pragma unroll
      for (int ktt = 0; ktt < 2; ++ktt)
        #pragma unroll
        for (int dt = 0; dt < 2; ++dt) {
          float vb = dt ? vb1 : vb0;
          f32x4 d0, d1;
          #pragma unroll
          for (int r = 0; r < 4; ++r) { d0[r] = acc[2 * ktt][dt][r] + vb; d1[r] = acc[2 * ktt + 1][dt][r] + vb; }
          bv[ktt][dt] = regroup(d0, d1, q, g);
        }
    }

    // ---------- attention (R13 logic; frags already in registers) ----------
    const unsigned short* bh2 = biasT + h * BSZ;

    f32x4 st[4][4];
    __builtin_amdgcn_s_setprio(1);
    #pragma unroll
    for (int it = 0; it < 4; ++it)
      #pragma unroll
      for (int jt = 0; jt < 4; ++jt)
        st[it][jt] = __builtin_amdgcn_mfma_f32_16x16x32_bf16(ak[jt], bq[it], zero, 0, 0, 0);
    __builtin_amdgcn_s_setprio(0);

    bf16x8 pa[4][2];
    #pragma unroll
    for (int it = 0; it < 4; ++it) {
      int i = it * 16 + q;
      int ic = i > 48 ? 48 : i;
      f32x4 pv4[4];
      f32x4 vm = {NINF, NINF, NINF, NINF};
      #pragma unroll
      for (int jt = 0; jt < 4; ++jt) {
        if (jt == 3 && g > 0) {
          pv4[3] = (f32x4){NINF, NINF, NINF, NINF};
        } else {
          u16x4 bu = *(const u16x4*)(bh2 + ic * BSTRIDE + jt * 16 + 4 * g);
          f32x4 m4 = *(const f32x4*)(wm + ic * BSTRIDE + jt * 16 + 4 * g);
          f32x4 sv = st[it][jt];
          #pragma unroll
          for (int r = 0; r < 4; ++r) sv[r] += bf2f(bu[r]) + m4[r];
          if (jt == 3) {            // g==0 here: j = 48+r, valid only r==0
            sv[1] = NINF; sv[2] = NINF; sv[3] = NINF;
          }
          pv4[jt] = sv;
          #pragma unroll
          for (int r = 0; r < 4; ++r) vm[r] = fmaxf(vm[r], sv[r]);
        }
      }
      float mx = fmaxf(fmaxf(vm[0], vm[1]), fmaxf(vm[2], vm[3]));
      mx = fmaxf(mx, __shfl_xor(mx, 16));
      mx = fmaxf(mx, __shfl_xor(mx, 32));
      f32x4 vs = zero;
      #pragma unroll
      for (int jt = 0; jt < 4; ++jt) {
        #pragma unroll
        for (int r = 0; r < 4; ++r) {
          float p = __expf(pv4[jt][r] - mx);   // -inf -> 0
          pv4[jt][r] = p;
          vs[r] += p;
        }
      }
      float sm = (vs[0] + vs[1]) + (vs[2] + vs[3]);
      sm += __shfl_xor(sm, 16);
      sm += __shfl_xor(sm, 32);
      float rv = 1.0f / sm;
      f32x4 pn[4];
      #pragma unroll
      for (int jt = 0; jt < 4; ++jt)
        #pragma unroll
        for (int r = 0; r < 4; ++r) pn[jt][r] = pv4[jt][r] * rv;
      pa[it][0] = regroup(pn[0], pn[1], q, g);
      pa[it][1] = regroup(pn[2], pn[3], q, g);
    }

    // O = P @ V, swapped: oacc[it][dt] r -> d = dt*16+4g+r, i = it*16+q (lane-local)
    f32x4 oacc[4][2] = {};
    __builtin_amdgcn_s_setprio(1);
    #pragma unroll
    for (int ktt = 0; ktt < 2; ++ktt)
      #pragma unroll
      for (int it = 0; it < 4; ++it)
        #pragma unroll
        for (int dt = 0; dt < 2; ++dt)
          oacc[it][dt] = __builtin_amdgcn_mfma_f32_16x16x32_bf16(bv[ktt][dt], pa[it][ktt], oacc[it][dt], 0, 0, 0);
    __builtin_amdgcn_s_setprio(0);

    // store fp32 output: per lane float4 at [b*49+i][h*32 + dt*16 + 4g]
    #pragma unroll
    for (int it = 0; it < 4; ++it) {
      int i = it * 16 + q;
      if (i < 49) {
        float* orow = out + (size_t)(b * 49 + i) * 512 + h * 32 + 4 * g;
        #pragma unroll
        for (int dt = 0; dt < 2; ++dt)
          *(f32x4*)(orow + dt * 16) = oacc[it][dt];
      }
    }
  }
}

// ---------------- launcher ----------------
extern "C" void kernel_launch(void* const* d_in, const int* in_sizes, int n_in,
                              void* d_out, int out_size, void* d_ws, size_t ws_size,
                              hipStream_t stream) {
  const float* x     = (const float*)d_in[0];
  const float* mask  = (const float*)d_in[1];
  const float* qkv_w = (const float*)d_in[2];
  const float* qkv_b = (const float*)d_in[3];
  const float* rpb   = (const float*)d_in[4];
  float* out = (float*)d_out;

  // workspace layout (bytes) — tiny now
  const size_t WB_OFF   = 0;          // 1536*512*2 = 1,572,864
  const size_t BIAS_OFF = 1572864;    // 16*2548*2  =    81,536
  const size_t MASK_OFF = 1654400;    // 64*2548*4  =   652,288
  const size_t NEED     = 2306688;
  if (ws_size < NEED) return;

  char* ws = (char*)d_ws;
  unsigned short* wbv   = (unsigned short*)(ws + WB_OFF);
  unsigned short* biasT = (unsigned short*)(ws + BIAS_OFF);
  float*          maskp = (float*)(ws + MASK_OFF);

  conv_f2b_k<<<512, 256, 0, stream>>>(qkv_w, wbv, 98304);      // w fp32 -> bf16
  build_bias_k<<<160, 256, 0, stream>>>(rpb, biasT);           // 16*2548
  build_maskp_k<<<637, 256, 0, stream>>>(mask, maskp);         // 64*2548
  fused_qkv_attn_k<<<2048, 512, 0, stream>>>(x, qkv_b, wbv, biasT, maskp, out);
}

// Round 16
// 430.021 us; speedup vs baseline: 3.4830x; 3.4830x over previous
//
#include <hip/hip_runtime.h>
#include <cstdint>
#include <cstddef>

typedef __bf16 bf16x8 __attribute__((ext_vector_type(8)));
typedef float f32x4 __attribute__((ext_vector_type(4)));
typedef unsigned short u16x8 __attribute__((ext_vector_type(8)));
typedef unsigned short u16x4 __attribute__((ext_vector_type(4)));
typedef unsigned int u32x2 __attribute__((ext_vector_type(2)));

#define VT_LD 56   // padded j-stride of V^T rows
#define BSTRIDE 52 // bias/mask row stride (elements)
#define BSZ 2548   // 49*52 per head
#define PLD 80     // P LDS row stride (shorts)

__device__ __forceinline__ unsigned short f2bf(float f) {
  unsigned int u = __builtin_bit_cast(unsigned int, f);
  u += 0x7FFFu + ((u >> 16) & 1u);   // RNE
  return (unsigned short)(u >> 16);
}
__device__ __forceinline__ float bf2f(unsigned short h) {
  unsigned int u = (unsigned int)h << 16;
  return __builtin_bit_cast(float, u);
}

__device__ __forceinline__ void gload_lds16(const void* g, void* l) {
  __builtin_amdgcn_global_load_lds((const __attribute__((address_space(1))) void*)g,
                                   (__attribute__((address_space(3))) void*)l, 16, 0, 0);
}

// ---------------- kernel 0: generic fp32 -> bf16 (vec8, grid-stride) ----------------
__global__ void conv_f2b_k(const float* __restrict__ src, unsigned short* __restrict__ dst, long n8) {
  long i = (long)blockIdx.x * blockDim.x + threadIdx.x;
  long stride = (long)gridDim.x * blockDim.x;
  for (; i < n8; i += stride) {
    float4 a = *(const float4*)(src + i * 8);
    float4 b = *(const float4*)(src + i * 8 + 4);
    u16x8 p;
    p[0]=f2bf(a.x); p[1]=f2bf(a.y); p[2]=f2bf(a.z); p[3]=f2bf(a.w);
    p[4]=f2bf(b.x); p[5]=f2bf(b.y); p[6]=f2bf(b.z); p[7]=f2bf(b.w);
    *(u16x8*)(dst + i * 8) = p;
  }
}

// ---------------- kernel 0b: bias table bf16 [16][49][52] (pad cols 49..51 = 0) ----------------
__global__ void build_bias_k(const float* __restrict__ rpb, unsigned short* __restrict__ biasT) {
  int idx = blockIdx.x * 256 + threadIdx.x;
  if (idx >= 16 * BSZ) return;
  int h = idx / BSZ;
  int rem = idx - h * BSZ;
  int i = rem / BSTRIDE, j = rem - (rem / BSTRIDE) * BSTRIDE;
  unsigned short v = 0;
  if (j < 49) {
    int r1 = i / 7, c1 = i - r1 * 7;
    int r2 = j / 7, c2 = j - r2 * 7;
    int ri = (r1 - r2 + 6) * 13 + (c1 - c2 + 6);
    v = f2bf(rpb[ri * 16 + h]);
  }
  biasT[idx] = v;
}

// ================= 256x256 8-phase GEMM (T2+T3+T4+T5 template port) =================
// BM=BN=256, BK=64, 512 thr (8 waves 2x4), LDS 128 KB = 2 dbuf x (A 32K + B 32K).
// Per operand tile: 2 planes [256][32] shorts (64B rows), chunk-swizzle c^((row>>1)&3).
// Stage stream for tile T: (T-2).ph3: B h0 | (T-2).ph4: B h1 + A h0 | (T-1).ph1: A h1.
// vmcnt(6) once per tile at ph4 -> next tile resident; never drain to 0 mid-loop.

#define STGA_H(KT, H) do {                                                                  \
    gload_lds16(ags + (size_t)(H)*65536 + (KT)*64,      Ab + ((KT)&1)*16384 + (H)*4096 + wid*512);        \
    gload_lds16(ags + (size_t)(H)*65536 + (KT)*64 + 32, Ab + ((KT)&1)*16384 + 8192 + (H)*4096 + wid*512); \
  } while (0)
#define STGB_H(KT, H) do {                                                                  \
    gload_lds16(bgs + (size_t)(H)*65536 + (KT)*64,      Bb + ((KT)&1)*16384 + (H)*4096 + wid*512);        \
    gload_lds16(bgs + (size_t)(H)*65536 + (KT)*64 + 32, Bb + ((KT)&1)*16384 + 8192 + (H)*4096 + wid*512); \
  } while (0)

#define MPH(R2, C2, BF, SWAPPED) do {                                                       \
    __builtin_amdgcn_s_setprio(1);                                                          \
    _Pragma("unroll")                                                                       \
    for (int rtl = 0; rtl < 4; ++rtl)                                                       \
      _Pragma("unroll")                                                                     \
      for (int ctl = 0; ctl < 2; ++ctl)                                                     \
        _Pragma("unroll")                                                                   \
        for (int ks2 = 0; ks2 < 2; ++ks2)                                                   \
          acc[(R2)*4+rtl][(C2)*2+ctl] = (SWAPPED)                                           \
            ? __builtin_amdgcn_mfma_f32_16x16x32_bf16(BF[ctl][ks2], af[rtl][ks2], acc[(R2)*4+rtl][(C2)*2+ctl], 0, 0, 0) \
            : __builtin_amdgcn_mfma_f32_16x16x32_bf16(af[rtl][ks2], BF[ctl][ks2], acc[(R2)*4+rtl][(C2)*2+ctl], 0, 0, 0); \
    __builtin_amdgcn_s_setprio(0);                                                          \
  } while (0)

#define TILE256(KT, BUF, SWAPPED) do {                                                      \
    _Pragma("unroll")                                                                       \
    for (int rtl = 0; rtl < 4; ++rtl) {                                                     \
      af[rtl][0] = *(const bf16x8*)(arp + (BUF)*16384 + rtl*512);                           \
      af[rtl][1] = *(const bf16x8*)(arp + (BUF)*16384 + 8192 + rtl*512);                    \
    }                                                                                       \
    _Pragma("unroll")                                                                       \
    for (int ctl = 0; ctl < 2; ++ctl) {                                                     \
      bf0[ctl][0] = *(const bf16x8*)(brp + (BUF)*16384 + ctl*512);                          \
      bf0[ctl][1] = *(const bf16x8*)(brp + (BUF)*16384 + 8192 + ctl*512);                   \
    }                                                                                       \
    if ((KT) + 1 < 8) { STGA_H((KT)+1, 1); }                                                \
    __builtin_amdgcn_s_barrier();                                                           \
    MPH(0, 0, bf0, SWAPPED);                                                                \
    __builtin_amdgcn_s_barrier();                                                           \
    _Pragma("unroll")                                                                       \
    for (int ctl = 0; ctl < 2; ++ctl) {                                                     \
      bf1[ctl][0] = *(const bf16x8*)(brp + (BUF)*16384 + 1024 + ctl*512);                   \
      bf1[ctl][1] = *(const bf16x8*)(brp + (BUF)*16384 + 8192 + 1024 + ctl*512);            \
    }                                                                                       \
    __builtin_amdgcn_s_barrier();                                                           \
    MPH(0, 1, bf1, SWAPPED);                                                                \
    __builtin_amdgcn_s_barrier();                                                           \
    _Pragma("unroll")                                                                       \
    for (int rtl = 0; rtl < 4; ++rtl) {                                                     \
      af[rtl][0] = *(const bf16x8*)(arp + (BUF)*16384 + 2048 + rtl*512);                    \
      af[rtl][1] = *(const bf16x8*)(arp + (BUF)*16384 + 8192 + 2048 + rtl*512);             \
    }                                                                                       \
    if ((KT) + 2 < 8) { STGB_H((KT)+2, 0); }                                                \
    __builtin_amdgcn_s_barrier();                                                           \
    MPH(1, 1, bf1, SWAPPED);                                                                \
    __builtin_amdgcn_s_barrier();                                                           \
    if ((KT) + 2 < 8) {                                                                     \
      STGB_H((KT)+2, 1); STGA_H((KT)+2, 0);                                                 \
      asm volatile("s_waitcnt vmcnt(6)" ::: "memory");                                      \
    } else if ((KT) + 1 < 8) {                                                              \
      asm volatile("s_waitcnt vmcnt(0)" ::: "memory");                                      \
    }                                                                                       \
    __builtin_amdgcn_s_barrier();                                                           \
    MPH(1, 0, bf0, SWAPPED);                                                                \
    __builtin_amdgcn_s_barrier();                                                           \
  } while (0)

__global__ __launch_bounds__(512, 2) void qkv_gemm256_k(
    const unsigned short* __restrict__ xb, const float* __restrict__ qkv_b,
    const unsigned short* __restrict__ wb,
    unsigned short* __restrict__ qs, unsigned short* __restrict__ kk,
    unsigned short* __restrict__ vt)
{
  __shared__ __align__(16) unsigned short smem[65536];   // 128 KB
  unsigned short* Ab = smem;            // [2 buf][2 planes][256][32]
  unsigned short* Bb = smem + 32768;

  int bid = blockIdx.x;
  int sw = (bid & 7) * 294 + (bid >> 3);   // 2352 % 8 == 0 -> bijective XCD swizzle
  int mt = sw / 6, nt = sw - mt * 6;       // 6 nt share one A panel
  long m0 = (long)mt * 256;
  int  n0 = nt * 256;
  int  s  = n0 >> 9;                       // nt 0,1->Q  2,3->K  4,5->V

  int t = threadIdx.x;
  int lane = t & 63, wid = t >> 6;
  int g = lane >> 4, q = lane & 15;
  int wm = wid >> 2, wn = wid & 3;         // 2 x 4 wave grid

  f32x4 acc[8][4] = {};
  bf16x8 af[4][2], bf0[2][2], bf1[2][2];

  int schunk = (t & 3) ^ ((t >> 3) & 3);
  const unsigned short* ags = xb + (m0 + (t >> 2)) * 512 + schunk * 8;
  const unsigned short* bgs = wb + (size_t)(n0 + (t >> 2)) * 512 + schunk * 8;

  int slot = (g ^ ((q >> 1) & 3)) * 8;
  const unsigned short* arp = Ab + (wm * 128 + q) * 32 + slot;
  const unsigned short* brp = Bb + (wn * 64 + q) * 32 + slot;

  // prologue: tile0 full (8 calls) + tile1 Bh0,Bh1,Ah0 (6 calls); tile1 Ah1 at t0.ph1
  STGB_H(0, 0); STGB_H(0, 1); STGA_H(0, 0); STGA_H(0, 1);
  STGB_H(1, 0); STGB_H(1, 1); STGA_H(1, 0);
  asm volatile("s_waitcnt vmcnt(6)" ::: "memory");
  __builtin_amdgcn_s_barrier();

  if (s < 2) {
    for (int kp = 0; kp < 4; ++kp) {
      TILE256(2 * kp, 0, 1);
      TILE256(2 * kp + 1, 1, 1);
    }
    // Q/K epilogue (swapped): m = m0+wm*128+rt*16+q lane-local; n = n0+wn*64+ct*16+4g+r
    unsigned short* dst = (s == 0) ? qs : kk;
    float sc2 = (s == 0) ? 0.17677669529663687f : 1.0f;
    float4 bi[4]; int hj[4], dj[4];
    #pragma unroll
    for (int ct = 0; ct < 4; ++ct) {
      int n4 = n0 + wn * 64 + ct * 16 + 4 * g;
      bi[ct] = *(const float4*)(qkv_b + n4);
      hj[ct] = (n4 >> 5) & 15;
      dj[ct] = n4 & 31;
    }
    #pragma unroll
    for (int rt = 0; rt < 8; ++rt) {
      unsigned int m = (unsigned int)m0 + wm * 128 + rt * 16 + q;
      unsigned int b = m / 49;
      unsigned int i = m - b * 49;
      size_t base = ((size_t)(b * 16) * 49 + i) * 32;
      #pragma unroll
      for (int ct = 0; ct < 4; ++ct) {
        f32x4 a = acc[rt][ct];
        unsigned int lo = (unsigned int)f2bf((a[0] + bi[ct].x) * sc2) | ((unsigned int)f2bf((a[1] + bi[ct].y) * sc2) << 16);
        unsigned int hi = (unsigned int)f2bf((a[2] + bi[ct].z) * sc2) | ((unsigned int)f2bf((a[3] + bi[ct].w) * sc2) << 16);
        u32x2 wv2 = {lo, hi};
        *(u32x2*)(dst + base + (size_t)hj[ct] * 1568 + dj[ct]) = wv2;
      }
    }
  } else {
    for (int kp = 0; kp < 4; ++kp) {
      TILE256(2 * kp, 0, 0);
      TILE256(2 * kp + 1, 1, 0);
    }
    // V epilogue (normal): 4 consecutive i in VT -> packed dword stores
    #pragma unroll
    for (int ct = 0; ct < 4; ++ct) {
      int n = n0 + wn * 64 + ct * 16 + q;
      float bias = qkv_b[n];
      int d = n & 31;
      int h = (n >> 5) & 15;
      #pragma unroll
      for (int rt = 0; rt < 8; ++rt) {
        unsigned int gm0 = (unsigned int)m0 + wm * 128 + rt * 16 + 4 * g;
        unsigned int b0 = gm0 / 49;
        unsigned int i0 = gm0 - b0 * 49;
        unsigned short hv[4];
        #pragma unroll
        for (int r = 0; r < 4; ++r) hv[r] = f2bf(acc[rt][ct][r] + bias);
        if (i0 <= 45) {
          unsigned short* base = vt + ((size_t)(b0 * 16 + h) * 32 + d) * VT_LD;
          if ((i0 & 1) == 0) {
            *(unsigned int*)(base + i0)     = (unsigned int)hv[0] | ((unsigned int)hv[1] << 16);
            *(unsigned int*)(base + i0 + 2) = (unsigned int)hv[2] | ((unsigned int)hv[3] << 16);
          } else {
            base[i0] = hv[0];
            *(unsigned int*)(base + i0 + 1) = (unsigned int)hv[1] | ((unsigned int)hv[2] << 16);
            base[i0 + 3] = hv[3];
          }
        } else {
          #pragma unroll
          for (int r = 0; r < 4; ++r) {
            unsigned int gm = gm0 + r;
            unsigned int b = gm / 49;
            unsigned int i = gm - b * 49;
            vt[((size_t)(b * 16 + h) * 32 + d) * VT_LD + i] = hv[r];
          }
        }
      }
    }
  }
}

// ---------------- kernel 2: fused window attention (R14 logic, occ 2 -> 3) ----------------
// LDS = 47 KB -> 3 blocks/CU fits (141 KB < 160); VGPR ~80 << 170-cap, no spill risk.
__global__ __launch_bounds__(256, 3) void win_attn_k(
    const unsigned short* __restrict__ qs, const unsigned short* __restrict__ kk,
    const unsigned short* __restrict__ vt, const unsigned short* __restrict__ biasT,
    const float* __restrict__ mask, float* __restrict__ out)
{
  __shared__ float mlds[BSZ];
  __shared__ unsigned short plds[4][64 * PLD];

  int b = blockIdx.x;
  int t = threadIdx.x;
  int lane = t & 63, wv = t >> 6;
  int g = lane >> 4, q = lane & 15;

  const float* msrc = mask + (size_t)(b & 63) * 2401;
  for (int idx = t; idx < BSZ; idx += 256) {
    int i = idx / BSTRIDE, j = idx - (idx / BSTRIDE) * BSTRIDE;
    mlds[idx] = (j < 49) ? msrc[i * 49 + j] : 0.0f;
  }
  __syncthreads();

  unsigned short* pl = plds[wv];
  const float NINF = -__builtin_inff();

  int rc[4];
  rc[0] = q; rc[1] = 16 + q; rc[2] = 32 + q; rc[3] = 48;

  int h0 = wv * 4;
  const unsigned short* qh = qs + (size_t)(b * 16 + h0) * (49 * 32);
  const unsigned short* kh = kk + (size_t)(b * 16 + h0) * (49 * 32);
  bf16x8 ak[4], bq[4];
  #pragma unroll
  for (int jt = 0; jt < 4; ++jt) ak[jt] = *(const bf16x8*)(kh + rc[jt] * 32 + 8 * g);
  #pragma unroll
  for (int it = 0; it < 4; ++it) bq[it] = *(const bf16x8*)(qh + rc[it] * 32 + 8 * g);

  #pragma unroll
  for (int hh = 0; hh < 4; ++hh) {
    int h = wv * 4 + hh;
    const unsigned short* vh  = vt + (size_t)(b * 16 + h) * (32 * VT_LD);
    const unsigned short* bh2 = biasT + h * BSZ;

    f32x4 zero = {0.f, 0.f, 0.f, 0.f};
    f32x4 st[4][4];
    __builtin_amdgcn_s_setprio(1);
    #pragma unroll
    for (int it = 0; it < 4; ++it)
      #pragma unroll
      for (int jt = 0; jt < 4; ++jt)
        st[it][jt] = __builtin_amdgcn_mfma_f32_16x16x32_bf16(ak[jt], bq[it], zero, 0, 0, 0);
    __builtin_amdgcn_s_setprio(0);

    bf16x8 akn[4], bqn[4];
    if (hh < 3) {
      const unsigned short* qh2 = qh + 49 * 32;
      const unsigned short* kh2 = kh + 49 * 32;
      #pragma unroll
      for (int jt = 0; jt < 4; ++jt) akn[jt] = *(const bf16x8*)(kh2 + rc[jt] * 32 + 8 * g);
      #pragma unroll
      for (int it = 0; it < 4; ++it) bqn[it] = *(const bf16x8*)(qh2 + rc[it] * 32 + 8 * g);
      qh = qh2; kh = kh2;
    }
    bf16x8 bv[2][2];
    #pragma unroll
    for (int ktt = 0; ktt < 2; ++ktt)
      #pragma unroll
      for (int dt = 0; dt < 2; ++dt)
        bv[ktt][dt] = *(const bf16x8*)(vh + (dt * 16 + q) * VT_LD + ktt * 32 + 8 * g);

    #pragma unroll
    for (int it = 0; it < 4; ++it) {
      int i = it * 16 + q;
      int ic = i > 48 ? 48 : i;
      f32x4 pv4[4];
      f32x4 vm = {NINF, NINF, NINF, NINF};
      #pragma unroll
      for (int jt = 0; jt < 4; ++jt) {
        if (jt == 3 && g > 0) {
          pv4[3] = (f32x4){NINF, NINF, NINF, NINF};
        } else {
          u16x4 bu = *(const u16x4*)(bh2 + ic * BSTRIDE + jt * 16 + 4 * g);
          f32x4 m4 = *(const f32x4*)(mlds + ic * BSTRIDE + jt * 16 + 4 * g);
          f32x4 sv = st[it][jt];
          #pragma unroll
          for (int r = 0; r < 4; ++r) sv[r] += bf2f(bu[r]) + m4[r];
          if (jt == 3) {
            sv[1] = NINF; sv[2] = NINF; sv[3] = NINF;
          }
          pv4[jt] = sv;
          #pragma unroll
          for (int r = 0; r < 4; ++r) vm[r] = fmaxf(vm[r], sv[r]);
        }
      }
      float mx = fmaxf(fmaxf(vm[0], vm[1]), fmaxf(vm[2], vm[3]));
      mx = fmaxf(mx, __shfl_xor(mx, 16));
      mx = fmaxf(mx, __shfl_xor(mx, 32));
      f32x4 vs = zero;
      #pragma unroll
      for (int jt = 0; jt < 4; ++jt) {
        #pragma unroll
        for (int r = 0; r < 4; ++r) {
          float p = __expf(pv4[jt][r] - mx);
          pv4[jt][r] = p;
          vs[r] += p;
        }
      }
      float sm = (vs[0] + vs[1]) + (vs[2] + vs[3]);
      sm += __shfl_xor(sm, 16);
      sm += __shfl_xor(sm, 32);
      float rv = 1.0f / sm;
      #pragma unroll
      for (int jt = 0; jt < 4; ++jt) {
        unsigned int lo = (unsigned int)f2bf(pv4[jt][0] * rv) | ((unsigned int)f2bf(pv4[jt][1] * rv) << 16);
        unsigned int hi = (unsigned int)f2bf(pv4[jt][2] * rv) | ((unsigned int)f2bf(pv4[jt][3] * rv) << 16);
        u32x2 w = {lo, hi};
        *(u32x2*)(pl + i * PLD + jt * 16 + 4 * g) = w;
      }
    }

    f32x4 oacc[4][2] = {};
    #pragma unroll
    for (int ktt = 0; ktt < 2; ++ktt) {
      bf16x8 pa[4];
      #pragma unroll
      for (int it = 0; it < 4; ++it)
        pa[it] = *(const bf16x8*)(pl + (it * 16 + q) * PLD + ktt * 32 + 8 * g);
      __builtin_amdgcn_s_setprio(1);
      #pragma unroll
      for (int it = 0; it < 4; ++it)
        #pragma unroll
        for (int dt = 0; dt < 2; ++dt)
          oacc[it][dt] = __builtin_amdgcn_mfma_f32_16x16x32_bf16(bv[ktt][dt], pa[it], oacc[it][dt], 0, 0, 0);
      __builtin_amdgcn_s_setprio(0);
    }

    #pragma unroll
    for (int it = 0; it < 4; ++it) {
      int i = it * 16 + q;
      if (i < 49) {
        float* orow = out + (size_t)(b * 49 + i) * 512 + h * 32 + 4 * g;
        #pragma unroll
        for (int dt = 0; dt < 2; ++dt)
          *(f32x4*)(orow + dt * 16) = oacc[it][dt];
      }
    }

    if (hh < 3) {
      #pragma unroll
      for (int jt = 0; jt < 4; ++jt) ak[jt] = akn[jt];
      #pragma unroll
      for (int it = 0; it < 4; ++it) bq[it] = bqn[it];
    }
  }
}

// ---------------- launcher ----------------
extern "C" void kernel_launch(void* const* d_in, const int* in_sizes, int n_in,
                              void* d_out, int out_size, void* d_ws, size_t ws_size,
                              hipStream_t stream) {
  const float* x     = (const float*)d_in[0];
  const float* mask  = (const float*)d_in[1];
  const float* qkv_w = (const float*)d_in[2];
  const float* qkv_b = (const float*)d_in[3];
  const float* rpb   = (const float*)d_in[4];
  float* out = (float*)d_out;

  // workspace layout (bytes)
  const size_t QS_OFF   = 0;                         // 2048*16*49*32*2 = 102,760,448
  const size_t KK_OFF   = 102760448;
  const size_t VT_OFF   = 205520896;                 // 2048*16*32*56*2 = 117,440,512
  const size_t BIAS_OFF = 322961408;                 // 16*2548*2      = 81,536
  const size_t WB_OFF   = 323042944;                 // 1536*512*2     = 1,572,864
  const size_t NEED     = 324615808;
  if (ws_size < NEED) return;

  char* ws = (char*)d_ws;
  unsigned short* qsb   = (unsigned short*)(ws + QS_OFF);
  unsigned short* kkb   = (unsigned short*)(ws + KK_OFF);
  unsigned short* vtb   = (unsigned short*)(ws + VT_OFF);
  unsigned short* biasT = (unsigned short*)(ws + BIAS_OFF);
  unsigned short* wb    = (unsigned short*)(ws + WB_OFF);

  // xb (bf16 x, 103 MB) lives in d_out (205 MB fp32) — dead until win_attn
  // fully overwrites it.
  unsigned short* xb = (unsigned short*)d_out;

  conv_f2b_k<<<2048, 256, 0, stream>>>(x, xb, 6422528);        // 100352*512/8
  conv_f2b_k<<<512, 256, 0, stream>>>(qkv_w, wb, 98304);       // 1536*512/8
  build_bias_k<<<160, 256, 0, stream>>>(rpb, biasT);           // 16*2548
  qkv_gemm256_k<<<2352, 512, 0, stream>>>(xb, qkv_b, wb, qsb, kkb, vtb);
  win_attn_k<<<2048, 256, 0, stream>>>(qsb, kkb, vtb, biasT, mask, out);
}